// Round 3
// baseline (6947.788 us; speedup 1.0000x reference)
//
#include <hip/hip_runtime.h>
#include <math.h>

#define B_  64
#define T_  150
#define L_  256
#define H_  512
#define E_  512
#define V_  1000
#define G4_ 2048   // 4*H
#define NBLK 256

__device__ __forceinline__ float sigmf(float x) { return 1.0f / (1.0f + expf(-x)); }

// ---------------- device-scope grid barrier (monotone counter, RMW poll) ----------------
__device__ __forceinline__ void gridbar(int* cnt, int tgt)
{
    __syncthreads();
    if (threadIdx.x == 0) {
        __threadfence();   // release: my block's global writes -> coherence point
        __hip_atomic_fetch_add(cnt, 1, __ATOMIC_RELAXED, __HIP_MEMORY_SCOPE_AGENT);
        while (__hip_atomic_fetch_add(cnt, 0, __ATOMIC_RELAXED, __HIP_MEMORY_SCOPE_AGENT)
               < NBLK * tgt)
            __builtin_amdgcn_s_sleep(1);
        __threadfence();   // acquire: discard stale cached lines before reading others' h
    }
    __syncthreads();
}

// ---------------- persistent serial LSTM recurrence: 150 steps, one launch ----------------
// Block bid owns h-cols {2bid, 2bid+1} -> gate cols {q*512+2bid+d}. Thread (b,q,ks):
// float2 partial over half the K range; LDS reduce; wave 0 applies the cell.
__global__ __launch_bounds__(512) void decoder_persistent(
    const int*   __restrict__ seq,    // [B][T]
    const float* __restrict__ G,      // [V][4H]
    const float* __restrict__ WhhT,   // [H][4H]
    float* hA, float* hB, float* cT,  // [H][B] each
    float* __restrict__ hbuf,         // rows (t,b): [T*B][H]
    int* cnt)
{
    const int tid = threadIdx.x;
    const int bid = blockIdx.x;
    const int b   = tid & 63;
    const int q   = (tid >> 6) & 3;
    const int ks  = tid >> 8;              // 0/1 (K half)
    const int c2  = q * H_ + 2 * bid;      // even gate col

    __shared__ float2 part[2][4][64];
    __shared__ float2 gsh[4][64];

    // zero my h/c columns
    if (tid < 128) {
        int d = tid >> 6;
        hA[(2 * bid + d) * 64 + b] = 0.f;
        cT[(2 * bid + d) * 64 + b] = 0.f;
    }
    gridbar(cnt, 1);

    for (int t = 0; t < T_; ++t) {
        const float* hcur = (t & 1) ? hB : hA;
        float*       hnxt = (t & 1) ? hA : hB;

        const float* hp = hcur + ks * 256 * 64 + b;
        const float* wp = WhhT + (size_t)(ks * 256) * G4_ + c2;
        float ax = 0.f, ay = 0.f;
        #pragma unroll 16
        for (int k = 0; k < 256; ++k) {
            float  hk = hp[(size_t)k * 64];
            float2 w  = *(const float2*)(wp + (size_t)k * G4_);
            ax += hk * w.x; ay += hk * w.y;
        }
        part[ks][q][b] = make_float2(ax, ay);
        __syncthreads();

        if (tid < 256) {
            const int v = seq[b * T_ + t];
            float2 g0 = part[0][q][b], g1 = part[1][q][b];
            float2 gv = *(const float2*)(G + (size_t)v * G4_ + c2);
            gsh[q][b] = make_float2(g0.x + g1.x + gv.x, g0.y + g1.y + gv.y);
        }
        __syncthreads();

        if (tid < 64) {
            float2 ig = gsh[0][b], fg = gsh[1][b], gg = gsh[2][b], og = gsh[3][b];
            int r0 = (2 * bid) * 64 + b, r1 = (2 * bid + 1) * 64 + b;
            float c0 = cT[r0], c1 = cT[r1];
            float cn0 = sigmf(fg.x) * c0 + sigmf(ig.x) * tanhf(gg.x);
            float cn1 = sigmf(fg.y) * c1 + sigmf(ig.y) * tanhf(gg.y);
            float h0 = sigmf(og.x) * tanhf(cn0);
            float h1 = sigmf(og.y) * tanhf(cn1);
            cT[r0] = cn0; cT[r1] = cn1;
            hnxt[r0] = h0; hnxt[r1] = h1;
            *(float2*)(hbuf + ((size_t)t * 64 + b) * H_ + 2 * bid) = make_float2(h0, h1);
        }
        gridbar(cnt, t + 2);
    }
}

// ---------------- generic NT GEMM: C[M][N] = op(A[M][K]) @ B[N][K]^T (+bias)(+accum)
template<bool RELU_A, bool ACCUM, bool REMAP>
__global__ __launch_bounds__(256) void gemm_nt(
    const float* __restrict__ A, size_t lda, size_t azs,
    const float* __restrict__ Bm, size_t ldb, size_t bzs,
    const float* __restrict__ bias1, const float* __restrict__ bias2,
    float* __restrict__ C, size_t ldc, size_t czs, int M, int N, int K)
{
    A  += blockIdx.z * azs;
    Bm += blockIdx.z * bzs;
    C  += blockIdx.z * czs;
    __shared__ __align__(16) float As[16][68];
    __shared__ __align__(16) float Bs[16][68];
    const int tid = threadIdx.x;
    const int m0 = blockIdx.x * 64;
    const int n0 = blockIdx.y * 64;
    const int lr = tid >> 2;
    const int lc = (tid & 3) << 2;
    const int tm = (tid & 15) << 2;
    const int tn = (tid >> 4) << 2;
    float acc[4][4] = {};

    for (int kb = 0; kb < K; kb += 16) {
        float4 a4 = make_float4(0.f, 0.f, 0.f, 0.f);
        int gm = m0 + lr;
        if (gm < M) a4 = *(const float4*)(A + (size_t)gm * lda + kb + lc);
        if (RELU_A) {
            a4.x = fmaxf(a4.x, 0.f); a4.y = fmaxf(a4.y, 0.f);
            a4.z = fmaxf(a4.z, 0.f); a4.w = fmaxf(a4.w, 0.f);
        }
        As[lc + 0][lr] = a4.x; As[lc + 1][lr] = a4.y;
        As[lc + 2][lr] = a4.z; As[lc + 3][lr] = a4.w;

        float4 b4 = make_float4(0.f, 0.f, 0.f, 0.f);
        int gn = n0 + lr;
        if (gn < N) b4 = *(const float4*)(Bm + (size_t)gn * ldb + kb + lc);
        Bs[lc + 0][lr] = b4.x; Bs[lc + 1][lr] = b4.y;
        Bs[lc + 2][lr] = b4.z; Bs[lc + 3][lr] = b4.w;
        __syncthreads();

        #pragma unroll
        for (int k = 0; k < 16; ++k) {
            float4 av = *(const float4*)&As[k][tm];
            float4 bv = *(const float4*)&Bs[k][tn];
            float af[4] = {av.x, av.y, av.z, av.w};
            float bf[4] = {bv.x, bv.y, bv.z, bv.w};
            #pragma unroll
            for (int i = 0; i < 4; ++i)
                #pragma unroll
                for (int j = 0; j < 4; ++j)
                    acc[i][j] += af[i] * bf[j];
        }
        __syncthreads();
    }

    #pragma unroll
    for (int i = 0; i < 4; ++i) {
        int gm = m0 + tm + i;
        if (gm >= M) continue;
        size_t row = REMAP ? ((size_t)(gm & 63) * T_ + (gm >> 6)) : (size_t)gm;
        #pragma unroll
        for (int j = 0; j < 4; ++j) {
            int gn = n0 + tn + j;
            if (gn >= N) continue;
            float v = acc[i][j];
            if (bias1) v += bias1[gn];
            if (bias2) v += bias2[gn];
            if (ACCUM) v += C[row * ldc + gn];
            C[row * ldc + gn] = v;
        }
    }
}

// ---------------- NN GEMM: C[M][N] = A[M][K] @ B[K][N]
__global__ __launch_bounds__(256) void gemm_nn(
    const float* __restrict__ A, size_t lda, size_t azs,
    const float* __restrict__ Bm, size_t ldb, size_t bzs,
    float* __restrict__ C, size_t ldc, size_t czs, int M, int N, int K)
{
    A  += blockIdx.z * azs;
    Bm += blockIdx.z * bzs;
    C  += blockIdx.z * czs;
    __shared__ __align__(16) float As[16][68];
    __shared__ __align__(16) float Bs[16][68];
    const int tid = threadIdx.x;
    const int m0 = blockIdx.x * 64;
    const int n0 = blockIdx.y * 64;
    const int lr = tid >> 2;
    const int lc = (tid & 3) << 2;
    const int br = tid >> 4;
    const int bc = (tid & 15) << 2;
    const int tm = (tid & 15) << 2;
    const int tn = (tid >> 4) << 2;
    float acc[4][4] = {};

    for (int kb = 0; kb < K; kb += 16) {
        float4 a4 = make_float4(0.f, 0.f, 0.f, 0.f);
        int gm = m0 + lr;
        if (gm < M) a4 = *(const float4*)(A + (size_t)gm * lda + kb + lc);
        As[lc + 0][lr] = a4.x; As[lc + 1][lr] = a4.y;
        As[lc + 2][lr] = a4.z; As[lc + 3][lr] = a4.w;

        float4 b4 = make_float4(0.f, 0.f, 0.f, 0.f);
        if (n0 + bc < N) b4 = *(const float4*)(Bm + (size_t)(kb + br) * ldb + n0 + bc);
        Bs[br][bc + 0] = b4.x; Bs[br][bc + 1] = b4.y;
        Bs[br][bc + 2] = b4.z; Bs[br][bc + 3] = b4.w;
        __syncthreads();

        #pragma unroll
        for (int k = 0; k < 16; ++k) {
            float4 av = *(const float4*)&As[k][tm];
            float4 bv = *(const float4*)&Bs[k][tn];
            float af[4] = {av.x, av.y, av.z, av.w};
            float bf[4] = {bv.x, bv.y, bv.z, bv.w};
            #pragma unroll
            for (int i = 0; i < 4; ++i)
                #pragma unroll
                for (int j = 0; j < 4; ++j)
                    acc[i][j] += af[i] * bf[j];
        }
        __syncthreads();
    }

    #pragma unroll
    for (int i = 0; i < 4; ++i) {
        int gm = m0 + tm + i;
        if (gm >= M) continue;
        #pragma unroll
        for (int j = 0; j < 4; ++j) {
            int gn = n0 + tn + j;
            if (gn >= N) continue;
            C[(size_t)gm * ldc + gn] = acc[i][j];
        }
    }
}

// ---------------- tiled transpose: out[C][R] = in[R][C]^T
__global__ __launch_bounds__(256) void transpose_k(
    const float* __restrict__ in, float* __restrict__ out, int R, int C)
{
    __shared__ float tile[32][33];
    int c0 = blockIdx.x * 32, r0 = blockIdx.y * 32;
    int x = threadIdx.x & 31, y = threadIdx.x >> 5;
    for (int i = y; i < 32; i += 8) {
        int r = r0 + i, cc = c0 + x;
        tile[i][x] = (r < R && cc < C) ? in[(size_t)r * C + cc] : 0.f;
    }
    __syncthreads();
    for (int i = y; i < 32; i += 8) {
        int cc = c0 + i, r = r0 + x;
        if (cc < C && r < R) out[(size_t)cc * R + r] = tile[x][i];
    }
}

// ---------------- softmax over rows of 256 (attention weights), 4 rows/block
__global__ __launch_bounds__(256) void att_softmax(float* __restrict__ att, int nrows)
{
    const int tid = threadIdx.x, lane = tid & 63, wave = tid >> 6;
    const int row = blockIdx.x * 4 + wave;
    if (row >= nrows) return;
    float4* p = (float4*)(att + (size_t)row * L_);
    float4 sc = p[lane];
    float mx = fmaxf(fmaxf(sc.x, sc.y), fmaxf(sc.z, sc.w));
    #pragma unroll
    for (int off = 32; off; off >>= 1) mx = fmaxf(mx, __shfl_xor(mx, off));
    float e0 = expf(sc.x - mx), e1 = expf(sc.y - mx);
    float e2 = expf(sc.z - mx), e3 = expf(sc.w - mx);
    float s = e0 + e1 + e2 + e3;
    #pragma unroll
    for (int off = 32; off; off >>= 1) s += __shfl_xor(s, off);
    float inv = 1.f / s;
    p[lane] = make_float4(e0 * inv, e1 * inv, e2 * inv, e3 * inv);
}

// ---------------- per-row log_softmax over V=1000, in place
__global__ __launch_bounds__(256) void logsoftmax_k(float* __restrict__ out)
{
    const int row = blockIdx.x;
    float* p = out + (size_t)row * V_;
    const int tid = threadIdx.x, lane = tid & 63, wave = tid >> 6;
    __shared__ float red[8];

    float vals[4];
    int n = 0;
    float mx = -INFINITY;
    for (int v = tid; v < V_; v += 256) { vals[n] = p[v]; mx = fmaxf(mx, vals[n]); ++n; }
    #pragma unroll
    for (int off = 32; off; off >>= 1) mx = fmaxf(mx, __shfl_xor(mx, off));
    if (lane == 0) red[wave] = mx;
    __syncthreads();
    mx = fmaxf(fmaxf(red[0], red[1]), fmaxf(red[2], red[3]));

    float s = 0.f;
    for (int i = 0; i < n; ++i) s += expf(vals[i] - mx);
    #pragma unroll
    for (int off = 32; off; off >>= 1) s += __shfl_xor(s, off);
    if (lane == 0) red[4 + wave] = s;
    __syncthreads();
    s = red[4] + red[5] + red[6] + red[7];

    const float lse = mx + logf(s);
    n = 0;
    for (int v = tid; v < V_; v += 256) { p[v] = vals[n] - lse; ++n; }
}

extern "C" void kernel_launch(void* const* d_in, const int* in_sizes, int n_in,
                              void* d_out, int out_size, void* d_ws, size_t ws_size,
                              hipStream_t stream)
{
    const float* cnn     = (const float*)d_in[0];
    const int*   seq     = (const int*)d_in[1];
    const float* embed   = (const float*)d_in[2];
    const float* W_ih    = (const float*)d_in[3];
    const float* b_ih    = (const float*)d_in[4];
    const float* W_hh    = (const float*)d_in[5];
    const float* b_hh    = (const float*)d_in[6];
    const float* W_hm    = (const float*)d_in[7];
    const float* W_om    = (const float*)d_in[8];
    const float* W_logit = (const float*)d_in[9];
    const float* b_logit = (const float*)d_in[10];
    float* out = (float*)d_out;

    float* ws = (float*)d_ws;
    float* WhhT = ws;                                  // 512*2048   = 1,048,576
    float* G    = WhhT + (size_t)H_ * G4_;             // 1000*2048  = 2,048,000
    float* hT_a = G + (size_t)V_ * G4_;                // 512*64
    float* hT_b = hT_a + (size_t)H_ * B_;
    float* cT   = hT_b + (size_t)H_ * B_;
    float* hbuf = cT + (size_t)H_ * B_;                // 9600*512 (rows (t,b))
    float* outv = hbuf + (size_t)B_ * T_ * H_;         // 9600*512
    int*   cnt  = (int*)(outv + (size_t)B_ * T_ * H_); // barrier counter
    // scratch inside d_out (dead before final logits write):
    float* mapped = out;                               // 9600*512 (rows (t,b)); reused as ctx
    float* attb   = out + (size_t)B_ * T_ * H_;        // 64*150*256

    hipMemsetAsync(cnt, 0, 2 * sizeof(int), stream);

    // pregate table: G[v][:] = relu(embed[v]) @ W_ih^T + b_ih + b_hh
    gemm_nt<true, false, false><<<dim3(16, 32, 1), 256, 0, stream>>>(
        embed, E_, 0, W_ih, E_, 0, b_ih, b_hh, G, G4_, 0, V_, G4_, E_);
    // WhhT = W_hh^T
    transpose_k<<<dim3(H_ / 32, G4_ / 32), 256, 0, stream>>>(W_hh, WhhT, G4_, H_);

    // ---- Phase 1: persistent serial LSTM recurrence (single launch) ----
    decoder_persistent<<<NBLK, 512, 0, stream>>>(seq, G, WhhT, hT_a, hT_b, cT, hbuf, cnt);

    // ---- Phase 2: batched over all 9600 (t,b) rows ----
    gemm_nt<false, false, false><<<dim3(150, 8, 1), 256, 0, stream>>>(
        hbuf, H_, 0, W_hm, H_, 0, nullptr, nullptr, mapped, H_, 0, B_ * T_, H_, H_);
    gemm_nt<false, false, false><<<dim3(3, 4, 64), 256, 0, stream>>>(
        mapped, (size_t)B_ * H_, H_,
        cnn, H_, (size_t)L_ * H_,
        nullptr, nullptr,
        attb, L_, (size_t)T_ * L_, T_, L_, H_);
    att_softmax<<<(B_ * T_ + 3) / 4, 256, 0, stream>>>(attb, B_ * T_);
    gemm_nn<<<dim3(3, 8, 64), 256, 0, stream>>>(
        attb, L_, (size_t)T_ * L_,
        cnn, H_, (size_t)L_ * H_,
        mapped, (size_t)B_ * H_, H_, T_, H_, L_);
    gemm_nt<false, false, false><<<dim3(150, 8, 1), 256, 0, stream>>>(
        mapped, H_, 0, W_om, 2 * H_, 0, nullptr, nullptr, outv, H_, 0, B_ * T_, H_, H_);
    gemm_nt<false, true, false><<<dim3(150, 8, 1), 256, 0, stream>>>(
        hbuf, H_, 0, W_om + H_, 2 * H_, 0, nullptr, nullptr, outv, H_, 0, B_ * T_, H_, H_);
    gemm_nt<false, false, true><<<dim3(150, 16, 1), 256, 0, stream>>>(
        outv, H_, 0, W_logit, H_, 0, b_logit, nullptr, out, V_, 0, B_ * T_, V_, H_);
    logsoftmax_k<<<B_ * T_, 256, 0, stream>>>(out);
}

// Round 4
// 3976.977 us; speedup vs baseline: 1.7470x; 1.7470x over previous
//
#include <hip/hip_runtime.h>
#include <math.h>

#define B_  64
#define T_  150
#define L_  256
#define H_  512
#define E_  512
#define V_  1000
#define G4_ 2048   // 4*H
#define NBLK 128

__device__ __forceinline__ float sigmf(float x) { return 1.0f / (1.0f + expf(-x)); }

// ---------------- device-scope grid barrier ----------------
// arrivals: one relaxed RMW per block; poll: agent-scope atomic LOAD (coherence-
// point read, no RMW serialization), s_sleep backoff. fences per Guideline 16.
__device__ __forceinline__ void gridbar(int* cnt, int tgt)
{
    __syncthreads();
    if (threadIdx.x == 0) {
        __threadfence();   // release: flush my block's h writes toward L3
        __hip_atomic_fetch_add(cnt, 1, __ATOMIC_RELAXED, __HIP_MEMORY_SCOPE_AGENT);
        while (__hip_atomic_load(cnt, __ATOMIC_RELAXED, __HIP_MEMORY_SCOPE_AGENT)
               < NBLK * tgt)
            __builtin_amdgcn_s_sleep(2);
        __threadfence();   // acquire: drop stale L1/L2 lines before reading others' h
    }
    __syncthreads();
}

// ---------------- persistent serial LSTM recurrence: 150 steps, one launch ----
// Block owns 4 h-cols j0..j0+3 -> 16 gate rows, whose weights live in LDS
// (loaded once -> immune to the per-step fence invalidation).
// Thread (b = tid&63, s = tid>>6): gate pair (q = s>>1, cols j0+jp, j0+jp+1),
// full K=512 accumulation; c-state kept in LDS (block-private).
__global__ __launch_bounds__(512) void decoder_persistent(
    const int*   __restrict__ seq,    // [B][T]
    const float* __restrict__ G,      // [V][4H] pregate table
    const float* __restrict__ Whh,    // [4H][H] ORIGINAL layout
    float* hA, float* hB,             // [H][B] double buffer
    float* __restrict__ hbuf,         // rows (t,b): [T*B][H]
    int* cnt)
{
    const int tid = threadIdx.x;
    const int bid = blockIdx.x;
    const int b   = tid & 63;
    const int s   = tid >> 6;          // 0..7
    const int q   = s >> 1;            // gate section 0..3
    const int jp  = (s & 1) << 1;      // 0 or 2
    const int j0  = bid * 4;

    __shared__ float2 wl[8][512];      // [s][k] weight slice, 32 KB
    __shared__ float  csh[4][64];      // c-state [j][b]
    __shared__ float  gsh[4][4][64];   // gates [q][j][b]

    // ---- one-time: load 16 rows of Whh (contiguous 2 KB each), transpose to wl
    for (int e = tid; e < 8192; e += 512) {
        int k  = e & 511;
        int rr = e >> 9;                       // 0..15: q' = rr>>2, jj = rr&3
        float v = Whh[(size_t)((rr >> 2) * H_ + j0 + (rr & 3)) * H_ + k];
        int ss = ((rr >> 2) << 1) | ((rr & 3) >> 1);
        ((float*)&wl[ss][k])[rr & 1] = v;
    }
    if (tid < 256) {
        int j = tid >> 6;
        hA[(j0 + j) * 64 + b] = 0.f;
        csh[j][b] = 0.f;
    }

    // prefetch step-0 pregate (independent of h)
    float2 gv;
    {
        const int v = seq[b * T_ + 0];
        gv = *(const float2*)(G + (size_t)v * G4_ + q * H_ + j0 + jp);
    }
    gridbar(cnt, 1);

    for (int t = 0; t < T_; ++t) {
        const float* hcur = (t & 1) ? hB : hA;
        float*       hnxt = (t & 1) ? hA : hB;

        float2 acc = gv;
        const float*  hp = hcur + b;
        const float2* wp = wl[s];
        #pragma unroll 16
        for (int k = 0; k < 512; ++k) {
            float  hk = hp[(size_t)k * 64];    // coalesced 256B/wave, L1/L2-shared
            float2 w  = wp[k];                 // LDS broadcast
            acc.x += hk * w.x; acc.y += hk * w.y;
        }
        gsh[q][jp + 0][b] = acc.x;
        gsh[q][jp + 1][b] = acc.y;

        // prefetch next step's pregate while others finish (hides under barrier)
        if (t + 1 < T_) {
            const int v = seq[b * T_ + t + 1];
            gv = *(const float2*)(G + (size_t)v * G4_ + q * H_ + j0 + jp);
        }
        __syncthreads();

        if (tid < 256) {
            int j = tid >> 6;
            float ig = gsh[0][j][b], fg = gsh[1][j][b];
            float gg = gsh[2][j][b], og = gsh[3][j][b];
            float c2 = sigmf(fg) * csh[j][b] + sigmf(ig) * tanhf(gg);
            float h2 = sigmf(og) * tanhf(c2);
            csh[j][b] = c2;
            hnxt[(j0 + j) * 64 + b] = h2;                    // coalesced per j
            hbuf[((size_t)t * 64 + b) * H_ + j0 + j] = h2;   // history for phase 2
        }
        gridbar(cnt, t + 2);
    }
}

// ---------------- generic NT GEMM: C[M][N] = op(A[M][K]) @ B[N][K]^T (+bias)
template<bool RELU_A, bool REMAP>
__global__ __launch_bounds__(256) void gemm_nt(
    const float* __restrict__ A, size_t lda, size_t azs,
    const float* __restrict__ Bm, size_t ldb, size_t bzs,
    const float* __restrict__ bias1, const float* __restrict__ bias2,
    float* __restrict__ C, size_t ldc, size_t czs, int M, int N, int K)
{
    A  += blockIdx.z * azs;
    Bm += blockIdx.z * bzs;
    C  += blockIdx.z * czs;
    __shared__ __align__(16) float As[16][68];
    __shared__ __align__(16) float Bs[16][68];
    const int tid = threadIdx.x;
    const int m0 = blockIdx.x * 64;
    const int n0 = blockIdx.y * 64;
    const int lr = tid >> 2;
    const int lc = (tid & 3) << 2;
    const int tm = (tid & 15) << 2;
    const int tn = (tid >> 4) << 2;
    float acc[4][4] = {};

    for (int kb = 0; kb < K; kb += 16) {
        float4 a4 = make_float4(0.f, 0.f, 0.f, 0.f);
        int gm = m0 + lr;
        if (gm < M) a4 = *(const float4*)(A + (size_t)gm * lda + kb + lc);
        if (RELU_A) {
            a4.x = fmaxf(a4.x, 0.f); a4.y = fmaxf(a4.y, 0.f);
            a4.z = fmaxf(a4.z, 0.f); a4.w = fmaxf(a4.w, 0.f);
        }
        As[lc + 0][lr] = a4.x; As[lc + 1][lr] = a4.y;
        As[lc + 2][lr] = a4.z; As[lc + 3][lr] = a4.w;

        float4 b4 = make_float4(0.f, 0.f, 0.f, 0.f);
        int gn = n0 + lr;
        if (gn < N) b4 = *(const float4*)(Bm + (size_t)gn * ldb + kb + lc);
        Bs[lc + 0][lr] = b4.x; Bs[lc + 1][lr] = b4.y;
        Bs[lc + 2][lr] = b4.z; Bs[lc + 3][lr] = b4.w;
        __syncthreads();

        #pragma unroll
        for (int k = 0; k < 16; ++k) {
            float4 av = *(const float4*)&As[k][tm];
            float4 bv = *(const float4*)&Bs[k][tn];
            float af[4] = {av.x, av.y, av.z, av.w};
            float bf[4] = {bv.x, bv.y, bv.z, bv.w};
            #pragma unroll
            for (int i = 0; i < 4; ++i)
                #pragma unroll
                for (int j = 0; j < 4; ++j)
                    acc[i][j] += af[i] * bf[j];
        }
        __syncthreads();
    }

    #pragma unroll
    for (int i = 0; i < 4; ++i) {
        int gm = m0 + tm + i;
        if (gm >= M) continue;
        size_t row = REMAP ? ((size_t)(gm & 63) * T_ + (gm >> 6)) : (size_t)gm;
        #pragma unroll
        for (int j = 0; j < 4; ++j) {
            int gn = n0 + tn + j;
            if (gn >= N) continue;
            float v = acc[i][j];
            if (bias1) v += bias1[gn];
            if (bias2) v += bias2[gn];
            C[row * ldc + gn] = v;
        }
    }
}

// ---------------- dual-A NT GEMM: C[M][N] = [A1|A2] @ Bm[N][1024]^T
// A1,A2 are [M][512]; K = 1024 spans A1 then A2 (fuses the W_om concat GEMM).
__global__ __launch_bounds__(256) void gemm_cat(
    const float* __restrict__ A1, const float* __restrict__ A2,
    const float* __restrict__ Bm, float* __restrict__ C, int M, int N)
{
    __shared__ __align__(16) float As[16][68];
    __shared__ __align__(16) float Bs[16][68];
    const int tid = threadIdx.x;
    const int m0 = blockIdx.x * 64;
    const int n0 = blockIdx.y * 64;
    const int lr = tid >> 2;
    const int lc = (tid & 3) << 2;
    const int tm = (tid & 15) << 2;
    const int tn = (tid >> 4) << 2;
    float acc[4][4] = {};

    for (int kb = 0; kb < 1024; kb += 16) {
        const float* Asel = (kb < 512) ? A1 : A2;
        int kk = kb & 511;
        float4 a4 = make_float4(0.f, 0.f, 0.f, 0.f);
        int gm = m0 + lr;
        if (gm < M) a4 = *(const float4*)(Asel + (size_t)gm * 512 + kk + lc);
        As[lc + 0][lr] = a4.x; As[lc + 1][lr] = a4.y;
        As[lc + 2][lr] = a4.z; As[lc + 3][lr] = a4.w;

        float4 b4 = make_float4(0.f, 0.f, 0.f, 0.f);
        int gn = n0 + lr;
        if (gn < N) b4 = *(const float4*)(Bm + (size_t)gn * 1024 + kb + lc);
        Bs[lc + 0][lr] = b4.x; Bs[lc + 1][lr] = b4.y;
        Bs[lc + 2][lr] = b4.z; Bs[lc + 3][lr] = b4.w;
        __syncthreads();

        #pragma unroll
        for (int k = 0; k < 16; ++k) {
            float4 av = *(const float4*)&As[k][tm];
            float4 bv = *(const float4*)&Bs[k][tn];
            float af[4] = {av.x, av.y, av.z, av.w};
            float bf[4] = {bv.x, bv.y, bv.z, bv.w};
            #pragma unroll
            for (int i = 0; i < 4; ++i)
                #pragma unroll
                for (int j = 0; j < 4; ++j)
                    acc[i][j] += af[i] * bf[j];
        }
        __syncthreads();
    }

    #pragma unroll
    for (int i = 0; i < 4; ++i) {
        int gm = m0 + tm + i;
        if (gm >= M) continue;
        #pragma unroll
        for (int j = 0; j < 4; ++j) {
            int gn = n0 + tn + j;
            if (gn >= N) continue;
            C[(size_t)gm * N + gn] = acc[i][j];
        }
    }
}

// ---------------- NN GEMM: C[M][N] = A[M][K] @ B[K][N]  (ctx = att @ cnn)
__global__ __launch_bounds__(256) void gemm_nn(
    const float* __restrict__ A, size_t lda, size_t azs,
    const float* __restrict__ Bm, size_t ldb, size_t bzs,
    float* __restrict__ C, size_t ldc, size_t czs, int M, int N, int K)
{
    A  += blockIdx.z * azs;
    Bm += blockIdx.z * bzs;
    C  += blockIdx.z * czs;
    __shared__ __align__(16) float As[16][68];
    __shared__ __align__(16) float Bs[16][68];
    const int tid = threadIdx.x;
    const int m0 = blockIdx.x * 64;
    const int n0 = blockIdx.y * 64;
    const int lr = tid >> 2;
    const int lc = (tid & 3) << 2;
    const int br = tid >> 4;
    const int bc = (tid & 15) << 2;
    const int tm = (tid & 15) << 2;
    const int tn = (tid >> 4) << 2;
    float acc[4][4] = {};

    for (int kb = 0; kb < K; kb += 16) {
        float4 a4 = make_float4(0.f, 0.f, 0.f, 0.f);
        int gm = m0 + lr;
        if (gm < M) a4 = *(const float4*)(A + (size_t)gm * lda + kb + lc);
        As[lc + 0][lr] = a4.x; As[lc + 1][lr] = a4.y;
        As[lc + 2][lr] = a4.z; As[lc + 3][lr] = a4.w;

        float4 b4 = make_float4(0.f, 0.f, 0.f, 0.f);
        if (n0 + bc < N) b4 = *(const float4*)(Bm + (size_t)(kb + br) * ldb + n0 + bc);
        Bs[br][bc + 0] = b4.x; Bs[br][bc + 1] = b4.y;
        Bs[br][bc + 2] = b4.z; Bs[br][bc + 3] = b4.w;
        __syncthreads();

        #pragma unroll
        for (int k = 0; k < 16; ++k) {
            float4 av = *(const float4*)&As[k][tm];
            float4 bv = *(const float4*)&Bs[k][tn];
            float af[4] = {av.x, av.y, av.z, av.w};
            float bf[4] = {bv.x, bv.y, bv.z, bv.w};
            #pragma unroll
            for (int i = 0; i < 4; ++i)
                #pragma unroll
                for (int j = 0; j < 4; ++j)
                    acc[i][j] += af[i] * bf[j];
        }
        __syncthreads();
    }

    #pragma unroll
    for (int i = 0; i < 4; ++i) {
        int gm = m0 + tm + i;
        if (gm >= M) continue;
        #pragma unroll
        for (int j = 0; j < 4; ++j) {
            int gn = n0 + tn + j;
            if (gn >= N) continue;
            C[(size_t)gm * ldc + gn] = acc[i][j];
        }
    }
}

// ---------------- softmax over rows of 256 (attention weights), 4 rows/block
__global__ __launch_bounds__(256) void att_softmax(float* __restrict__ att, int nrows)
{
    const int tid = threadIdx.x, lane = tid & 63, wave = tid >> 6;
    const int row = blockIdx.x * 4 + wave;
    if (row >= nrows) return;
    float4* p = (float4*)(att + (size_t)row * L_);
    float4 sc = p[lane];
    float mx = fmaxf(fmaxf(sc.x, sc.y), fmaxf(sc.z, sc.w));
    #pragma unroll
    for (int off = 32; off; off >>= 1) mx = fmaxf(mx, __shfl_xor(mx, off));
    float e0 = expf(sc.x - mx), e1 = expf(sc.y - mx);
    float e2 = expf(sc.z - mx), e3 = expf(sc.w - mx);
    float s = e0 + e1 + e2 + e3;
    #pragma unroll
    for (int off = 32; off; off >>= 1) s += __shfl_xor(s, off);
    float inv = 1.f / s;
    p[lane] = make_float4(e0 * inv, e1 * inv, e2 * inv, e3 * inv);
}

// ---------------- per-row log_softmax over V=1000, in place
__global__ __launch_bounds__(256) void logsoftmax_k(float* __restrict__ out)
{
    const int row = blockIdx.x;
    float* p = out + (size_t)row * V_;
    const int tid = threadIdx.x, lane = tid & 63, wave = tid >> 6;
    __shared__ float red[8];

    float vals[4];
    int n = 0;
    float mx = -INFINITY;
    for (int v = tid; v < V_; v += 256) { vals[n] = p[v]; mx = fmaxf(mx, vals[n]); ++n; }
    #pragma unroll
    for (int off = 32; off; off >>= 1) mx = fmaxf(mx, __shfl_xor(mx, off));
    if (lane == 0) red[wave] = mx;
    __syncthreads();
    mx = fmaxf(fmaxf(red[0], red[1]), fmaxf(red[2], red[3]));

    float s = 0.f;
    for (int i = 0; i < n; ++i) s += expf(vals[i] - mx);
    #pragma unroll
    for (int off = 32; off; off >>= 1) s += __shfl_xor(s, off);
    if (lane == 0) red[4 + wave] = s;
    __syncthreads();
    s = red[4] + red[5] + red[6] + red[7];

    const float lse = mx + logf(s);
    n = 0;
    for (int v = tid; v < V_; v += 256) { p[v] = vals[n] - lse; ++n; }
}

extern "C" void kernel_launch(void* const* d_in, const int* in_sizes, int n_in,
                              void* d_out, int out_size, void* d_ws, size_t ws_size,
                              hipStream_t stream)
{
    const float* cnn     = (const float*)d_in[0];
    const int*   seq     = (const int*)d_in[1];
    const float* embed   = (const float*)d_in[2];
    const float* W_ih    = (const float*)d_in[3];
    const float* b_ih    = (const float*)d_in[4];
    const float* W_hh    = (const float*)d_in[5];
    const float* b_hh    = (const float*)d_in[6];
    const float* W_hm    = (const float*)d_in[7];
    const float* W_om    = (const float*)d_in[8];
    const float* W_logit = (const float*)d_in[9];
    const float* b_logit = (const float*)d_in[10];
    float* out = (float*)d_out;

    float* ws = (float*)d_ws;
    float* G    = ws;                                  // 1000*2048 = 2,048,000
    float* hT_a = G + (size_t)V_ * G4_;                // 512*64
    float* hT_b = hT_a + (size_t)H_ * B_;
    float* hbuf = hT_b + (size_t)H_ * B_;              // 9600*512 (rows (t,b))
    float* outv = hbuf + (size_t)B_ * T_ * H_;         // 9600*512
    int*   cnt  = (int*)(outv + (size_t)B_ * T_ * H_);
    // scratch inside d_out (dead before the final logits write):
    float* mapped = out;                               // 9600*512; reused as ctx
    float* attb   = out + (size_t)B_ * T_ * H_;        // 9600*256

    hipMemsetAsync(cnt, 0, sizeof(int), stream);

    // pregate table: G[v][:] = relu(embed[v]) @ W_ih^T + b_ih + b_hh
    gemm_nt<true, false><<<dim3(16, 32, 1), 256, 0, stream>>>(
        embed, E_, 0, W_ih, E_, 0, b_ih, b_hh, G, G4_, 0, V_, G4_, E_);

    // ---- Phase 1: persistent serial LSTM recurrence (weights LDS-resident) ----
    decoder_persistent<<<NBLK, 512, 0, stream>>>(seq, G, W_hh, hT_a, hT_b, hbuf, cnt);

    // ---- Phase 2: batched over all 9600 (t,b) rows ----
    // mapped = h @ W_hm^T
    gemm_nt<false, false><<<dim3(150, 8, 1), 256, 0, stream>>>(
        hbuf, H_, 0, W_hm, H_, 0, nullptr, nullptr, mapped, H_, 0, B_ * T_, H_, H_);
    // att[b][t][l] = mapped[(t,b)] . cnn[b][l]
    gemm_nt<false, false><<<dim3(3, 4, 64), 256, 0, stream>>>(
        mapped, (size_t)B_ * H_, H_,
        cnn, H_, (size_t)L_ * H_,
        nullptr, nullptr,
        attb, L_, (size_t)T_ * L_, T_, L_, H_);
    att_softmax<<<(B_ * T_ + 3) / 4, 256, 0, stream>>>(attb, B_ * T_);
    // ctx = att @ cnn   (overwrites mapped)
    gemm_nn<<<dim3(3, 8, 64), 256, 0, stream>>>(
        attb, L_, (size_t)T_ * L_,
        cnn, H_, (size_t)L_ * H_,
        mapped, (size_t)B_ * H_, H_, T_, H_, L_);
    // out = [ctx | h] @ W_om^T   (single fused K=1024 GEMM)
    gemm_cat<<<dim3(150, 8, 1), 256, 0, stream>>>(
        mapped, hbuf, W_om, outv, B_ * T_, H_);
    // logits (+bias), remapping rows (t,b) -> (b,t) into d_out
    gemm_nt<false, true><<<dim3(150, 16, 1), 256, 0, stream>>>(
        outv, H_, 0, W_logit, H_, 0, b_logit, nullptr, out, V_, 0, B_ * T_, V_, H_);
    logsoftmax_k<<<B_ * T_, 256, 0, stream>>>(out);
}